// Round 1
// baseline (59.071 us; speedup 1.0000x reference)
//
#include <hip/hip_runtime.h>
#include <math.h>

// GaussianScalarCompander: per-element companding quantizer.
//   y      = 0.5*erf(x/sqrt(6)) + 0.5
//   k      = nearest uniform center = clamp(floor(y*N), 0, N-1)   (N=1024)
//   y_hat  = (k+0.5)/N
//   x_hat  = sqrt(6)*erfinv(2*y_hat - 1)
//   lik    = CDF_Y((k+1)/N) - CDF_Y(k/N),  CDF_Y(v)=0.5*erf(sqrt(3)*erfinv(2v-1))+0.5
// Outputs concatenated flat: x_hat[B], likelihood[B], y_hat[B].

#define B_ELEMS 262144
#define NC      1024

__device__ __forceinline__ void compand1(float x, float& xh, float& lik, float& yh) {
    const float INV_SQRT6 = 0.40824829046386302f;  // 1/sqrt(6)
    const float SQRT6     = 2.4494897427831781f;
    const float SQRT3     = 1.7320508075688772f;

    float y = 0.5f * erff(x * INV_SQRT6) + 0.5f;
    int k = (int)floorf(y * (float)NC);
    k = max(0, min(NC - 1, k));
    float kf = (float)k;

    yh = (kf + 0.5f) * (1.0f / (float)NC);
    xh = SQRT6 * erfinvf(2.0f * yh - 1.0f);

    // CDF_Y at k/N and (k+1)/N; endpoints are exactly 0 and 1.
    float lo = (k == 0) ? 0.0f
             : fmaf(0.5f, erff(SQRT3 * erfinvf(fmaf(kf, 2.0f / (float)NC, -1.0f))), 0.5f);
    float hi = (k == NC - 1) ? 1.0f
             : fmaf(0.5f, erff(SQRT3 * erfinvf(fmaf(kf + 1.0f, 2.0f / (float)NC, -1.0f))), 0.5f);
    lik = hi - lo;
}

__global__ __launch_bounds__(256) void GaussianScalarCompander_kernel(
        const float* __restrict__ x, float* __restrict__ out) {
    int i = blockIdx.x * 256 + threadIdx.x;          // float4 index, [0, B/4)
    const float4* __restrict__ x4 = (const float4*)x;
    float4 xv = x4[i];

    float4 xh, lk, yh;
    compand1(xv.x, xh.x, lk.x, yh.x);
    compand1(xv.y, xh.y, lk.y, yh.y);
    compand1(xv.z, xh.z, lk.z, yh.z);
    compand1(xv.w, xh.w, lk.w, yh.w);

    float4* __restrict__ o_xh = (float4*)out;
    float4* __restrict__ o_lk = (float4*)(out + B_ELEMS);
    float4* __restrict__ o_yh = (float4*)(out + 2 * B_ELEMS);
    o_xh[i] = xh;
    o_lk[i] = lk;
    o_yh[i] = yh;
}

extern "C" void kernel_launch(void* const* d_in, const int* in_sizes, int n_in,
                              void* d_out, int out_size, void* d_ws, size_t ws_size,
                              hipStream_t stream) {
    const float* x = (const float*)d_in[0];
    // d_in[1] (centers) unused: centers[k] = (k+0.5)/1024 exactly, derived analytically.
    float* out = (float*)d_out;

    const int n4 = B_ELEMS / 4;                 // 65536 float4 work items
    dim3 block(256);
    dim3 grid(n4 / 256);                        // 256 blocks
    GaussianScalarCompander_kernel<<<grid, block, 0, stream>>>(x, out);
}

// Round 2
// 58.546 us; speedup vs baseline: 1.0090x; 1.0090x over previous
//
#include <hip/hip_runtime.h>
#include <math.h>

// GaussianScalarCompander — table-based formulation.
// All per-index quantities (x_hat(k), likelihood(k)) are precomputed once into
// d_ws by a tiny kernel (3k transcendentals total), then the main kernel does
// only ONE erff per element plus two LDS table gathers.
//
// Outputs concatenated flat: x_hat[B], likelihood[B], y_hat[B].

#define B_ELEMS 262144
#define NC      1024

#define INV_SQRT6 0.40824829046386302f
#define SQRT6     2.4494897427831781f
#define SQRT3     1.7320508075688772f

// ---- kernel 1: build tables into workspace --------------------------------
// xh_tab[k]  = sqrt(6)*erfinv(2*(k+0.5)/N - 1)
// lik_tab[k] = CDF_Y((k+1)/N) - CDF_Y(k/N),  CDF_Y(v)=0.5*erf(sqrt(3)*erfinv(2v-1))+0.5
__global__ __launch_bounds__(1024) void build_tables_kernel(
        float* __restrict__ xh_tab, float* __restrict__ lik_tab) {
    __shared__ float cdf[NC + 1];
    const int k = threadIdx.x;                    // 0..1023

    float c;
    if (k == 0) {
        c = 0.0f;                                 // CDF_Y(0) = 0 exactly
    } else {
        float v = (float)k * (1.0f / (float)NC);
        c = fmaf(0.5f, erff(SQRT3 * erfinvf(fmaf(v, 2.0f, -1.0f))), 0.5f);
    }
    cdf[k] = c;
    if (k == NC - 1) cdf[NC] = 1.0f;              // CDF_Y(1) = 1 exactly

    float yh = ((float)k + 0.5f) * (1.0f / (float)NC);
    xh_tab[k] = SQRT6 * erfinvf(fmaf(yh, 2.0f, -1.0f));

    __syncthreads();
    lik_tab[k] = cdf[k + 1] - cdf[k];
}

// ---- kernel 2: per-element map --------------------------------------------
__global__ __launch_bounds__(256) void compand_kernel(
        const float* __restrict__ x, float* __restrict__ out,
        const float* __restrict__ xh_tab, const float* __restrict__ lik_tab) {
    __shared__ float s_xh[NC];
    __shared__ float s_lik[NC];
    const int t = threadIdx.x;

    // Stage both 4 KB tables into LDS, vectorized: 256 threads x one float4 each.
    ((float4*)s_xh)[t]  = ((const float4*)xh_tab)[t];
    ((float4*)s_lik)[t] = ((const float4*)lik_tab)[t];
    __syncthreads();

    const int i = blockIdx.x * 256 + t;
    float xv = x[i];
    float y  = fmaf(0.5f, erff(xv * INV_SQRT6), 0.5f);
    int k = (int)floorf(y * (float)NC);
    k = max(0, min(NC - 1, k));

    out[i]               = s_xh[k];
    out[B_ELEMS + i]     = s_lik[k];
    out[2 * B_ELEMS + i] = ((float)k + 0.5f) * (1.0f / (float)NC);
}

extern "C" void kernel_launch(void* const* d_in, const int* in_sizes, int n_in,
                              void* d_out, int out_size, void* d_ws, size_t ws_size,
                              hipStream_t stream) {
    const float* x = (const float*)d_in[0];
    // d_in[1] (centers) unused: centers[k] = (k+0.5)/1024 exactly, derived analytically.
    float* out = (float*)d_out;

    float* xh_tab  = (float*)d_ws;            // 1024 floats
    float* lik_tab = (float*)d_ws + NC;       // 1024 floats

    build_tables_kernel<<<1, NC, 0, stream>>>(xh_tab, lik_tab);

    dim3 block(256);
    dim3 grid(B_ELEMS / 256);                 // 1024 blocks -> 4 waves/SIMD
    compand_kernel<<<grid, block, 0, stream>>>(x, out, xh_tab, lik_tab);
}